// Round 12
// baseline (236.986 us; speedup 1.0000x reference)
//
#include <hip/hip_runtime.h>

#define FN   128    // nodes per graph
#define HDIM 128    // hidden dim
#define NH   4      // heads, layer 0
#define HSZ  32     // head dim, layer 0
#define EB   1024   // base edges per graph
#define ET   1152   // edges incl. self loops
#define RSW  132    // padded LDS row stride (words)

typedef __attribute__((ext_vector_type(8))) short bf16x8;
typedef __attribute__((ext_vector_type(4))) float f32x4;
typedef unsigned int u32;
typedef unsigned short u16;

union U8 { bf16x8 v; u32 u[4]; };

__device__ __forceinline__ u32 pack_hl(float v) {
  const u32 u = __float_as_uint(v);
  const u32 hib = u & 0xFFFF0000u;
  const float lo = v - __uint_as_float(hib);
  return hib | (__float_as_uint(lo) >> 16);
}
__device__ __forceinline__ float unpack_val(u32 p) {
  return __uint_as_float(p & 0xFFFF0000u) + __uint_as_float(p << 16);
}

__device__ __forceinline__ void unpack_frag(const u32* __restrict__ q,
                                            bf16x8& hi, bf16x8& lo)
{
  const uint4 p0 = *(const uint4*)(q);
  const uint4 p1 = *(const uint4*)(q + 4);
  U8 H, L;
  H.u[0] = (p0.x >> 16) | (p0.y & 0xFFFF0000u);
  L.u[0] = (p0.x & 0xFFFFu) | (p0.y << 16);
  H.u[1] = (p0.z >> 16) | (p0.w & 0xFFFF0000u);
  L.u[1] = (p0.z & 0xFFFFu) | (p0.w << 16);
  H.u[2] = (p1.x >> 16) | (p1.y & 0xFFFF0000u);
  L.u[2] = (p1.x & 0xFFFFu) | (p1.y << 16);
  H.u[3] = (p1.z >> 16) | (p1.w & 0xFFFF0000u);
  L.u[3] = (p1.z & 0xFFFFu) | (p1.w << 16);
  hi = H.v; lo = L.v;
}

// ---------------- W -> split bf16 hi/lo, B-fragment layout (r3-verified) ----
// wf: [layer 2][hilo 2][ctile 8][kc 4][lane 64][j 8] bf16
__global__ __launch_bounds__(256) void prep_w_kernel(
    const float* __restrict__ g0w, const float* __restrict__ g1w,
    u16* __restrict__ wf)
{
  const int idx = blockIdx.x * 256 + threadIdx.x;   // 32768 total
  const int layer = idx >> 14;
  const int r = idx & 16383;
  const int c  = r >> 11;
  const int kc = (r >> 9) & 3;
  const int l  = (r >> 3) & 63;
  const int j  = r & 7;
  const int k = kc * 32 + (l >> 4) * 8 + j;
  const int n = c * 16 + (l & 15);
  const float* W = layer ? g1w : g0w;
  const float v = W[k * HDIM + n];
  const u32 u = __float_as_uint(v);
  const u32 hib = u & 0xFFFF0000u;
  const float lo = v - __uint_as_float(hib);
  wf[layer * 32768 + r]         = (u16)(u >> 16);
  wf[layer * 32768 + 16384 + r] = (u16)(__float_as_uint(lo) >> 16);
}

// MFMA GEMM, 8 waves: wave tile 32 cols (cg) x 64 rows (rh half, 4 stripes).
// B-frags streamed pre-split from global (L2-hot). acc[stripe][ct].
__device__ __forceinline__ void mfma_gemm_acc(const u32* __restrict__ F,
                                              const u16* __restrict__ wf,
                                              int t, f32x4 acc[4][2])
{
  const int w = t >> 6, lane = t & 63;
  const int cg = w & 3, rh = w >> 2;         // cg 0..3, rh 0..1
  const int m = lane & 15, quad = lane >> 4;

  #pragma unroll
  for (int s = 0; s < 4; ++s)
    #pragma unroll
    for (int ct = 0; ct < 2; ++ct) acc[s][ct] = (f32x4){0.f, 0.f, 0.f, 0.f};

  const u16* bbase = wf + (cg * 8) * 512 + lane * 8;   // ct +2048, kc +512

  #pragma unroll
  for (int kc = 0; kc < 4; ++kc) {
    bf16x8 bhi[2], blo[2];
    #pragma unroll
    for (int ct = 0; ct < 2; ++ct) {
      const u16* bp = bbase + ct * 2048 + kc * 512;
      bhi[ct] = *(const bf16x8*)bp;
      blo[ct] = *(const bf16x8*)(bp + 16384);
    }
    #pragma unroll
    for (int s = 0; s < 4; ++s) {
      const u32* ap = F + (rh * 64 + s * 16 + m) * RSW + quad * 8 + kc * 32;
      bf16x8 ahi, alo;
      unpack_frag(ap, ahi, alo);
      #pragma unroll
      for (int ct = 0; ct < 2; ++ct) {
        acc[s][ct] = __builtin_amdgcn_mfma_f32_16x16x32_bf16(ahi, bhi[ct], acc[s][ct], 0, 0, 0);
        acc[s][ct] = __builtin_amdgcn_mfma_f32_16x16x32_bf16(alo, bhi[ct], acc[s][ct], 0, 0, 0);
        acc[s][ct] = __builtin_amdgcn_mfma_f32_16x16x32_bf16(ahi, blo[ct], acc[s][ct], 0, 0, 0);
      }
    }
  }
}

// store acc -> plain f32 sg (into F); C/D: col = lane&15, row = quad*4 + reg
__device__ __forceinline__ void store_acc(float* __restrict__ sg, int t,
                                          const f32x4 acc[4][2])
{
  const int w = t >> 6, lane = t & 63;
  const int cg = w & 3, rh = w >> 2;
  const int m = lane & 15, quad = lane >> 4;
  #pragma unroll
  for (int s = 0; s < 4; ++s) {
    const int row0 = rh * 64 + s * 16 + quad * 4;
    #pragma unroll
    for (int ct = 0; ct < 2; ++ct)
      #pragma unroll
      for (int r = 0; r < 4; ++r)
        sg[(row0 + r) * RSW + cg * 32 + ct * 16 + m] = acc[s][ct][r];
  }
}

// ---------------- fused per-graph GNN (512 threads, 8 waves, in-place) ------
__global__ __launch_bounds__(512, 4) void gnn_fused_kernel(
    const float* __restrict__ x, const int* __restrict__ ei,
    const float* __restrict__ w_in, const float* __restrict__ b_in,
    const float* __restrict__ g0as, const float* __restrict__ g0ad,
    const float* __restrict__ g0b,
    const float* __restrict__ bn0g, const float* __restrict__ bn0b,
    const float* __restrict__ bn0m, const float* __restrict__ bn0v,
    const float* __restrict__ g1as, const float* __restrict__ g1ad,
    const float* __restrict__ g1b,
    const float* __restrict__ bn1g, const float* __restrict__ bn1b,
    const float* __restrict__ bn1m, const float* __restrict__ bn1v,
    const float* __restrict__ w1, const float* __restrict__ b1,
    const float* __restrict__ w2, const float* __restrict__ b2,
    const u16* __restrict__ wf,
    float* __restrict__ out)
{
  __shared__ u32   F[FN * RSW];        // 67.6 KB packed feat <-> f32 sg
  __shared__ int   s_src[ET];          // src (pool/MLP scratch later)
  __shared__ int   s_rp[FN + 1];
  __shared__ float s_scr[1024];        // deg/fill -> es/ed -> pool partials

  float* s_es = s_scr;                 // [head][n]
  float* s_ed = s_scr + 512;

  const int t = threadIdx.x;
  const int b = blockIdx.x;
  f32x4 acc[4][2];

  // ================= per-block CSR build =================
  int* s_deg  = (int*)s_scr;
  int* s_fill = s_deg + 128;
  const int ed0 = ei[EB + t], ed1 = ei[EB + 512 + t];
  const int es0 = ei[t],      es1 = ei[512 + t];
  if (t < 2 * FN) s_deg[t] = 0;
  __syncthreads();
  atomicAdd(&s_deg[ed0], 1);
  atomicAdd(&s_deg[ed1], 1);

  // ---- input projection + ReLU -> F (packed)
  {
    const int j = t & 127, q = t >> 7;
    const float wv = w_in[j], bv = b_in[j];
    for (int n = q * 32; n < q * 32 + 32; ++n) {
      const float v = fmaxf(fmaf(x[(size_t)b * FN + n], wv, bv), 0.f);
      F[n * RSW + j] = pack_hl(v);
    }
  }
  __syncthreads();
  if (t < 64) {                         // wave-0 exclusive scan of (deg+1)
    const int v0 = s_deg[2 * t] + 1, v1 = s_deg[2 * t + 1] + 1;
    const int p = v0 + v1;
    int sc = p;
    #pragma unroll
    for (int off = 1; off < 64; off <<= 1) {
      const int o = __shfl_up(sc, off, 64);
      if (t >= off) sc += o;
    }
    s_rp[2 * t] = sc - p;
    s_rp[2 * t + 1] = sc - v1;
    if (t == 63) s_rp[128] = sc;        // == ET
  }
  __syncthreads();
  {
    int p = s_rp[ed0] + atomicAdd(&s_fill[ed0], 1);
    s_src[p] = es0;
    p = s_rp[ed1] + atomicAdd(&s_fill[ed1], 1);
    s_src[p] = es1;
  }
  if (t < FN) s_src[s_rp[t + 1] - 1] = t;   // self loop in reserved last slot
  __syncthreads();

  // ======================= GAT layer 0 =======================
  mfma_gemm_acc(F, wf, t, acc);
  __syncthreads();                       // all packed reads done
  store_acc((float*)F, t, acc);          // F now f32 sg
  __syncthreads();

  // logits per (head, node)
  {
    const int hh = t >> 7, n = t & 127;
    const float* row = (const float*)F + n * RSW + hh * HSZ;
    float accs = 0.f, accd = 0.f;
    #pragma unroll
    for (int s = 0; s < 8; ++s) {
      const int d = ((n + s) & 7) * 4;
      const float4 v  = *(const float4*)(row + d);
      const float4 as = *(const float4*)(g0as + hh * HSZ + d);
      const float4 ad = *(const float4*)(g0ad + hh * HSZ + d);
      accs += v.x*as.x + v.y*as.y + v.z*as.z + v.w*as.w;
      accd += v.x*ad.x + v.y*ad.y + v.z*ad.z + v.w*ad.w;
    }
    s_es[hh * 128 + n] = accs;
    s_ed[hh * 128 + n] = accd;
  }
  __syncthreads();

  // ---- aggregation: thread = (node, head-colgroup); exp once per (e,h)
  //      per pass; acc held in 32 regs across barrier; in-place writeback
  {
    const int n = t >> 2, c = t & 3;       // node, head == col-group
    const int cb = c * 32;
    const float* Ff = (const float*)F;
    const int e0 = s_rp[n], e1 = s_rp[n + 1];
    const float edv = s_ed[c * 128 + n];
    const float* esb = s_es + c * 128;
    float sum = 0.f;
    for (int e = e0; e < e1; ++e) {
      float v = esb[s_src[e]] + edv;
      v = (v > 0.f) ? v : 0.2f * v;
      sum += __expf(v);
    }
    const float rsv = 1.f / sum;
    float4 a[8];
    #pragma unroll
    for (int i = 0; i < 8; ++i) a[i] = make_float4(0.f, 0.f, 0.f, 0.f);
    for (int e = e0; e < e1; ++e) {
      const int s = s_src[e];
      float v = esb[s] + edv;
      v = (v > 0.f) ? v : 0.2f * v;
      const float al = __expf(v);
      const float* rp_ = Ff + s * RSW + cb;
      #pragma unroll
      for (int i = 0; i < 8; ++i) {
        const float4 vv = *(const float4*)(rp_ + i * 4);
        a[i].x = fmaf(al, vv.x, a[i].x); a[i].y = fmaf(al, vv.y, a[i].y);
        a[i].z = fmaf(al, vv.z, a[i].z); a[i].w = fmaf(al, vv.w, a[i].w);
      }
    }
    __syncthreads();                     // all sg reads done -> overwrite F
    #pragma unroll
    for (int i = 0; i < 8; ++i) {
      const int cc = cb + i * 4;
      const float4 bb = *(const float4*)&g0b[cc];
      const float4 bm = *(const float4*)&bn0m[cc];
      const float4 bv = *(const float4*)&bn0v[cc];
      const float4 bg = *(const float4*)&bn0g[cc];
      const float4 bt = *(const float4*)&bn0b[cc];
      uint4 p;
      p.x = pack_hl(fmaxf((a[i].x * rsv + bb.x - bm.x) * (bg.x * rsqrtf(bv.x + 1e-5f)) + bt.x, 0.f));
      p.y = pack_hl(fmaxf((a[i].y * rsv + bb.y - bm.y) * (bg.y * rsqrtf(bv.y + 1e-5f)) + bt.y, 0.f));
      p.z = pack_hl(fmaxf((a[i].z * rsv + bb.z - bm.z) * (bg.z * rsqrtf(bv.z + 1e-5f)) + bt.z, 0.f));
      p.w = pack_hl(fmaxf((a[i].w * rsv + bb.w - bm.w) * (bg.w * rsqrtf(bv.w + 1e-5f)) + bt.w, 0.f));
      *(uint4*)(F + n * RSW + cc) = p;
    }
  }
  __syncthreads();

  // ======================= GAT layer 1 (1 head) =======================
  mfma_gemm_acc(F, wf + 32768, t, acc);
  __syncthreads();
  store_acc((float*)F, t, acc);
  __syncthreads();

  if (t < FN) {
    const int n = t;
    const float* row = (const float*)F + n * RSW;
    float accs = 0.f, accd = 0.f;
    #pragma unroll 8
    for (int s = 0; s < 32; ++s) {
      const int d = ((n + s) & 31) * 4;
      const float4 v  = *(const float4*)(row + d);
      const float4 as = *(const float4*)(g1as + d);
      const float4 ad = *(const float4*)(g1ad + d);
      accs += v.x*as.x + v.y*as.y + v.z*as.z + v.w*as.w;
      accd += v.x*ad.x + v.y*ad.y + v.z*ad.z + v.w*ad.w;
    }
    s_es[n] = accs;
    s_ed[n] = accd;
  }
  __syncthreads();

  {
    const int n = t >> 2, c = t & 3;
    const int cb = c * 32;
    const float* Ff = (const float*)F;
    const int e0 = s_rp[n], e1 = s_rp[n + 1];
    const float edv = s_ed[n];
    float sum = 0.f;
    for (int e = e0; e < e1; ++e) {
      float v = s_es[s_src[e]] + edv;
      v = (v > 0.f) ? v : 0.2f * v;
      sum += __expf(v);
    }
    const float rsv = 1.f / sum;
    float4 a[8];
    #pragma unroll
    for (int i = 0; i < 8; ++i) a[i] = make_float4(0.f, 0.f, 0.f, 0.f);
    for (int e = e0; e < e1; ++e) {
      const int s = s_src[e];
      float v = s_es[s] + edv;
      v = (v > 0.f) ? v : 0.2f * v;
      const float al = __expf(v);
      const float* rp_ = Ff + s * RSW + cb;
      #pragma unroll
      for (int i = 0; i < 8; ++i) {
        const float4 vv = *(const float4*)(rp_ + i * 4);
        a[i].x = fmaf(al, vv.x, a[i].x); a[i].y = fmaf(al, vv.y, a[i].y);
        a[i].z = fmaf(al, vv.z, a[i].z); a[i].w = fmaf(al, vv.w, a[i].w);
      }
    }
    __syncthreads();
    #pragma unroll
    for (int i = 0; i < 8; ++i) {
      const int cc = cb + i * 4;
      const float4 bb = *(const float4*)&g1b[cc];
      const float4 bm = *(const float4*)&bn1m[cc];
      const float4 bv = *(const float4*)&bn1v[cc];
      const float4 bg = *(const float4*)&bn1g[cc];
      const float4 bt = *(const float4*)&bn1b[cc];
      uint4 p;
      p.x = pack_hl(fmaxf((a[i].x * rsv + bb.x - bm.x) * (bg.x * rsqrtf(bv.x + 1e-5f)) + bt.x, 0.f));
      p.y = pack_hl(fmaxf((a[i].y * rsv + bb.y - bm.y) * (bg.y * rsqrtf(bv.y + 1e-5f)) + bt.y, 0.f));
      p.z = pack_hl(fmaxf((a[i].z * rsv + bb.z - bm.z) * (bg.z * rsqrtf(bv.z + 1e-5f)) + bt.z, 0.f));
      p.w = pack_hl(fmaxf((a[i].w * rsv + bb.w - bm.w) * (bg.w * rsqrtf(bv.w + 1e-5f)) + bt.w, 0.f));
      *(uint4*)(F + n * RSW + cc) = p;
    }
  }
  __syncthreads();

  // ---- mean pool (packed F) + MLP head
  {
    const int j = t & 127, q = t >> 7;
    float p = 0.f;
    for (int n = q * 32; n < q * 32 + 32; ++n) p += unpack_val(F[n * RSW + j]);
    s_scr[q * 128 + j] = p;
  }
  __syncthreads();
  float* s_mean = (float*)s_src;        // s_src dead
  if (t < FN) {
    s_mean[t] = (s_scr[t] + s_scr[t + 128] + s_scr[t + 256] + s_scr[t + 384])
                * (1.f / 128.f);
  }
  __syncthreads();
  float* s_part = s_mean + 128;
  {
    const int j = t & 63, part = t >> 6;
    float a = 0.f;
    #pragma unroll
    for (int k = part * 16; k < part * 16 + 16; ++k)
      a = fmaf(s_mean[k], w1[k * 64 + j], a);
    s_part[part * 64 + j] = a;
  }
  __syncthreads();
  if (t < 64) {
    float a = b1[t];
    #pragma unroll
    for (int p = 0; p < 8; ++p) a += s_part[p * 64 + t];
    a = fmaxf(a, 0.f);
    float v = a * w2[t];
    #pragma unroll
    for (int off = 32; off > 0; off >>= 1) v += __shfl_down(v, off, 64);
    if (t == 0) out[b] = v + b2[0];
  }
}

extern "C" void kernel_launch(void* const* d_in, const int* in_sizes, int n_in,
                              void* d_out, int out_size, void* d_ws, size_t ws_size,
                              hipStream_t stream)
{
  const float* x    = (const float*)d_in[0];
  const int*   ei   = (const int*)d_in[1];
  const float* w_in = (const float*)d_in[2];
  const float* b_in = (const float*)d_in[3];
  const float* g0w  = (const float*)d_in[4];
  const float* g0as = (const float*)d_in[5];
  const float* g0ad = (const float*)d_in[6];
  const float* g0b  = (const float*)d_in[7];
  const float* bn0g = (const float*)d_in[8];
  const float* bn0b = (const float*)d_in[9];
  const float* bn0m = (const float*)d_in[10];
  const float* bn0v = (const float*)d_in[11];
  const float* g1w  = (const float*)d_in[12];
  const float* g1as = (const float*)d_in[13];
  const float* g1ad = (const float*)d_in[14];
  const float* g1b  = (const float*)d_in[15];
  const float* bn1g = (const float*)d_in[16];
  const float* bn1b = (const float*)d_in[17];
  const float* bn1m = (const float*)d_in[18];
  const float* bn1v = (const float*)d_in[19];
  const float* w1   = (const float*)d_in[20];
  const float* b1   = (const float*)d_in[21];
  const float* w2   = (const float*)d_in[22];
  const float* b2   = (const float*)d_in[23];

  u16* wf = (u16*)d_ws;   // 2 layers x 2 hilo x 16384 bf16 = 128 KB

  prep_w_kernel<<<128, 256, 0, stream>>>(g0w, g1w, wf);
  gnn_fused_kernel<<<1024, 512, 0, stream>>>(x, ei, w_in, b_in,
      g0as, g0ad, g0b, bn0g, bn0b, bn0m, bn0v,
      g1as, g1ad, g1b, bn1g, bn1b, bn1m, bn1v,
      w1, b1, w2, b2, wf, (float*)d_out);
}

// Round 13
// 196.518 us; speedup vs baseline: 1.2059x; 1.2059x over previous
//
#include <hip/hip_runtime.h>

#define FN   128    // nodes per graph
#define HDIM 128    // hidden dim
#define NH   4      // heads, layer 0
#define HSZ  32     // head dim, layer 0
#define EB   1024   // base edges per graph
#define ET   1152   // edges incl. self loops
#define RSW  132    // padded LDS row stride (words)

typedef __attribute__((ext_vector_type(8))) short bf16x8;
typedef __attribute__((ext_vector_type(4))) float f32x4;
typedef unsigned int u32;
typedef unsigned short u16;

union U8 { bf16x8 v; u32 u[4]; };

__device__ __forceinline__ u32 pack_hl(float v) {
  const u32 u = __float_as_uint(v);
  const u32 hib = u & 0xFFFF0000u;
  const float lo = v - __uint_as_float(hib);
  return hib | (__float_as_uint(lo) >> 16);
}
__device__ __forceinline__ float unpack_val(u32 p) {
  return __uint_as_float(p & 0xFFFF0000u) + __uint_as_float(p << 16);
}

__device__ __forceinline__ void unpack_frag(const u32* __restrict__ q,
                                            bf16x8& hi, bf16x8& lo)
{
  const uint4 p0 = *(const uint4*)(q);
  const uint4 p1 = *(const uint4*)(q + 4);
  U8 H, L;
  H.u[0] = (p0.x >> 16) | (p0.y & 0xFFFF0000u);
  L.u[0] = (p0.x & 0xFFFFu) | (p0.y << 16);
  H.u[1] = (p0.z >> 16) | (p0.w & 0xFFFF0000u);
  L.u[1] = (p0.z & 0xFFFFu) | (p0.w << 16);
  H.u[2] = (p1.x >> 16) | (p1.y & 0xFFFF0000u);
  L.u[2] = (p1.x & 0xFFFFu) | (p1.y << 16);
  H.u[3] = (p1.z >> 16) | (p1.w & 0xFFFF0000u);
  L.u[3] = (p1.z & 0xFFFFu) | (p1.w << 16);
  hi = H.v; lo = L.v;
}

// ---------------- W -> split bf16 hi/lo, B-fragment layout (r3-verified) ----
// wf: [layer 2][hilo 2][ctile 8][kc 4][lane 64][j 8] bf16
__global__ __launch_bounds__(256) void prep_w_kernel(
    const float* __restrict__ g0w, const float* __restrict__ g1w,
    u16* __restrict__ wf)
{
  const int idx = blockIdx.x * 256 + threadIdx.x;   // 32768 total
  const int layer = idx >> 14;
  const int r = idx & 16383;
  const int c  = r >> 11;
  const int kc = (r >> 9) & 3;
  const int l  = (r >> 3) & 63;
  const int j  = r & 7;
  const int k = kc * 32 + (l >> 4) * 8 + j;
  const int n = c * 16 + (l & 15);
  const float* W = layer ? g1w : g0w;
  const float v = W[k * HDIM + n];
  const u32 u = __float_as_uint(v);
  const u32 hib = u & 0xFFFF0000u;
  const float lo = v - __uint_as_float(hib);
  wf[layer * 32768 + r]         = (u16)(u >> 16);
  wf[layer * 32768 + 16384 + r] = (u16)(__float_as_uint(lo) >> 16);
}

// MFMA GEMM (r5/r10-verified): acc = feat(packed shl) @ W, B-frags streamed
// pre-split from global (L2-hot). kc-outer: no spill.
__device__ __forceinline__ void mfma_gemm_acc(const u32* __restrict__ shl,
                                              const u16* __restrict__ wf,
                                              int t, f32x4 acc[2][2])
{
  const int w = t >> 6, lane = t & 63;
  const int cg = w & 3, rh = w >> 2;
  const int m = lane & 15, quad = lane >> 4;

  #pragma unroll
  for (int s = 0; s < 2; ++s)
    #pragma unroll
    for (int ct = 0; ct < 2; ++ct) acc[s][ct] = (f32x4){0.f, 0.f, 0.f, 0.f};

  const u32* ap0 = shl + (rh * 32 + m) * RSW + quad * 8;
  const u32* ap1 = shl + (rh * 32 + 16 + m) * RSW + quad * 8;
  const u16* bbase = wf + (cg * 8) * 512 + lane * 8;   // ct +2048, kc +512

  #pragma unroll
  for (int kc = 0; kc < 4; ++kc) {
    bf16x8 bhi[2], blo[2];
    #pragma unroll
    for (int ct = 0; ct < 2; ++ct) {
      const u16* bp = bbase + ct * 2048 + kc * 512;
      bhi[ct] = *(const bf16x8*)bp;
      blo[ct] = *(const bf16x8*)(bp + 16384);
    }
    bf16x8 a0hi, a0lo, a1hi, a1lo;
    unpack_frag(ap0 + kc * 32, a0hi, a0lo);
    unpack_frag(ap1 + kc * 32, a1hi, a1lo);
    #pragma unroll
    for (int ct = 0; ct < 2; ++ct) {
      acc[0][ct] = __builtin_amdgcn_mfma_f32_16x16x32_bf16(a0hi, bhi[ct], acc[0][ct], 0, 0, 0);
      acc[0][ct] = __builtin_amdgcn_mfma_f32_16x16x32_bf16(a0lo, bhi[ct], acc[0][ct], 0, 0, 0);
      acc[0][ct] = __builtin_amdgcn_mfma_f32_16x16x32_bf16(a0hi, blo[ct], acc[0][ct], 0, 0, 0);
      acc[1][ct] = __builtin_amdgcn_mfma_f32_16x16x32_bf16(a1hi, bhi[ct], acc[1][ct], 0, 0, 0);
      acc[1][ct] = __builtin_amdgcn_mfma_f32_16x16x32_bf16(a1lo, bhi[ct], acc[1][ct], 0, 0, 0);
      acc[1][ct] = __builtin_amdgcn_mfma_f32_16x16x32_bf16(a1hi, blo[ct], acc[1][ct], 0, 0, 0);
    }
  }
}

// store acc -> sg (f32); C/D: col = lane&15, row = quad*4 + reg
__device__ __forceinline__ void store_acc(float* __restrict__ sg, int t,
                                          const f32x4 acc[2][2])
{
  const int w = t >> 6, lane = t & 63;
  const int cg = w & 3, rh = w >> 2;
  const int m = lane & 15, quad = lane >> 4;
  #pragma unroll
  for (int s = 0; s < 2; ++s) {
    const int row0 = rh * 32 + s * 16 + quad * 4;
    #pragma unroll
    for (int ct = 0; ct < 2; ++ct)
      #pragma unroll
      for (int r = 0; r < 4; ++r)
        sg[(row0 + r) * RSW + cg * 32 + ct * 16 + m] = acc[s][ct][r];
  }
}

// ---------------- fused per-graph GNN (1024 threads, 16 waves) ----------------
__global__ __launch_bounds__(1024) void gnn_fused_kernel(
    const float* __restrict__ x, const int* __restrict__ ei,
    const float* __restrict__ w_in, const float* __restrict__ b_in,
    const float* __restrict__ g0as, const float* __restrict__ g0ad,
    const float* __restrict__ g0b,
    const float* __restrict__ bn0g, const float* __restrict__ bn0b,
    const float* __restrict__ bn0m, const float* __restrict__ bn0v,
    const float* __restrict__ g1as, const float* __restrict__ g1ad,
    const float* __restrict__ g1b,
    const float* __restrict__ bn1g, const float* __restrict__ bn1b,
    const float* __restrict__ bn1m, const float* __restrict__ bn1v,
    const float* __restrict__ w1, const float* __restrict__ b1,
    const float* __restrict__ w2, const float* __restrict__ b2,
    const u16* __restrict__ wf,
    float* __restrict__ out)
{
  __shared__ u32   shl[FN * RSW];       // packed hi|lo features
  __shared__ float sg[FN * RSW];        // GEMM output (f32)
  __shared__ float s_alpha[NH * ET];    // exp numerators (also logit partials)
  __shared__ int   s_src[ET];           // src | dst<<8
  __shared__ int   s_rp[FN + 1];
  __shared__ float s_es[512];           // [head][n]
  __shared__ float s_ed[512];           // [head][n] logits -> 1/sum after numerators
  const int t = threadIdx.x;
  const int b = blockIdx.x;
  f32x4 acc[2][2];

  // ================= per-block CSR build =================
  int* s_deg  = (int*)s_alpha;
  int* s_fill = s_deg + 128;
  const int e_dst = ei[EB + t];
  const int e_src = ei[t];
  if (t < 2 * FN) s_deg[t] = 0;
  __syncthreads();
  atomicAdd(&s_deg[e_dst], 1);

  // ---- input projection + ReLU -> shl
  {
    const int j = t & 127, q = t >> 7;
    const float wv = w_in[j], bv = b_in[j];
    for (int n = q * 16; n < q * 16 + 16; ++n) {
      const float v = fmaxf(fmaf(x[(size_t)b * FN + n], wv, bv), 0.f);
      shl[n * RSW + j] = pack_hl(v);
    }
  }
  __syncthreads();
  if (t < 64) {                         // wave-0 exclusive scan of (deg+1)
    const int v0 = s_deg[2 * t] + 1, v1 = s_deg[2 * t + 1] + 1;
    const int p = v0 + v1;
    int sc = p;
    #pragma unroll
    for (int off = 1; off < 64; off <<= 1) {
      const int o = __shfl_up(sc, off, 64);
      if (t >= off) sc += o;
    }
    s_rp[2 * t] = sc - p;
    s_rp[2 * t + 1] = sc - v1;
    if (t == 63) s_rp[128] = sc;        // == ET
  }
  __syncthreads();
  {
    const int p = s_rp[e_dst] + atomicAdd(&s_fill[e_dst], 1);
    s_src[p] = e_src | (e_dst << 8);
  }
  if (t < FN) s_src[s_rp[t + 1] - 1] = t | (t << 8);
  __syncthreads();

  // ======================= GAT layer 0 =======================
  mfma_gemm_acc(shl, wf, t, acc);
  store_acc(sg, t, acc);
  __syncthreads();

  // logits per (head, node)
  if (t < 512) {
    const int hh = t >> 7, n = t & 127;
    const float* row = sg + n * RSW + hh * HSZ;
    float accs = 0.f, accd = 0.f;
    #pragma unroll
    for (int s = 0; s < 8; ++s) {
      const int d = ((n + s) & 7) * 4;
      const float4 v  = *(const float4*)(row + d);
      const float4 as = *(const float4*)(g0as + hh * HSZ + d);
      const float4 ad = *(const float4*)(g0ad + hh * HSZ + d);
      accs += v.x*as.x + v.y*as.y + v.z*as.z + v.w*as.w;
      accd += v.x*ad.x + v.y*ad.y + v.z*ad.z + v.w*ad.w;
    }
    s_es[hh * 128 + n] = accs;
    s_ed[hh * 128 + n] = accd;
  }
  __syncthreads();

  // single-pass edge-parallel softmax numerators (no max; r7-verified)
  {
    #pragma unroll
    for (int i = t; i < NH * EB; i += 1024) {
      const int h = i >> 10, e = i & 1023;
      const int sd = s_src[e];
      float v = s_es[h * 128 + (sd & 127)] + s_ed[h * 128 + (sd >> 8)];
      v = (v > 0.f) ? v : 0.2f * v;
      s_alpha[h * ET + e] = __expf(v);
    }
    if (t < 512) {                      // tail edges 1024..1151
      const int h = t >> 7, e = EB + (t & 127);
      const int sd = s_src[e];
      float v = s_es[h * 128 + (sd & 127)] + s_ed[h * 128 + (sd >> 8)];
      v = (v > 0.f) ? v : 0.2f * v;
      s_alpha[h * ET + e] = __expf(v);
    }
  }
  __syncthreads();

  // per-(head,node) 1/sum, computed ONCE (s_ed is dead post-numerators)
  if (t < 512) {
    const int hh = t >> 7, n = t & 127;
    const int e0 = s_rp[n], e1 = s_rp[n + 1];
    float sum = 0.f;
    for (int e = e0; e < e1; ++e) sum += s_alpha[hh * ET + e];
    s_ed[hh * 128 + n] = 1.f / sum;
  }
  __syncthreads();

  // aggregation + bias + BN + ReLU -> shl  (thread: 2 nodes x 8 cols)
  {
    const int cg = t & 15, rg = t >> 4;
    const int c0 = cg * 4, c1 = 64 + cg * 4;
    const int hhA = cg >> 3, hhB = 2 + hhA;
    const float4 bbA = *(const float4*)&g0b[c0],  bbB = *(const float4*)&g0b[c1];
    const float4 bmA = *(const float4*)&bn0m[c0], bmB = *(const float4*)&bn0m[c1];
    const float4 bvA = *(const float4*)&bn0v[c0], bvB = *(const float4*)&bn0v[c1];
    const float4 bgA = *(const float4*)&bn0g[c0], bgB = *(const float4*)&bn0g[c1];
    const float4 btA = *(const float4*)&bn0b[c0], btB = *(const float4*)&bn0b[c1];
    const float g0_ = bgA.x * rsqrtf(bvA.x + 1e-5f), g1_ = bgA.y * rsqrtf(bvA.y + 1e-5f);
    const float g2_ = bgA.z * rsqrtf(bvA.z + 1e-5f), g3_ = bgA.w * rsqrtf(bvA.w + 1e-5f);
    const float g4_ = bgB.x * rsqrtf(bvB.x + 1e-5f), g5_ = bgB.y * rsqrtf(bvB.y + 1e-5f);
    const float g6_ = bgB.z * rsqrtf(bvB.z + 1e-5f), g7_ = bgB.w * rsqrtf(bvB.w + 1e-5f);
    #pragma unroll
    for (int h2 = 0; h2 < 2; ++h2) {
      const int n = rg + h2 * 64;
      const int e0 = s_rp[n], e1 = s_rp[n + 1];
      const float rsvA = s_ed[hhA * 128 + n];
      const float rsvB = s_ed[hhB * 128 + n];
      float4 a0 = make_float4(0.f, 0.f, 0.f, 0.f);
      float4 a1 = make_float4(0.f, 0.f, 0.f, 0.f);
      for (int e = e0; e < e1; ++e) {
        const int s = s_src[e] & 127;
        const float alA = s_alpha[hhA * ET + e];
        const float alB = s_alpha[hhB * ET + e];
        const float4 v0 = *(const float4*)(sg + s * RSW + c0);
        const float4 v1 = *(const float4*)(sg + s * RSW + c1);
        a0.x = fmaf(alA, v0.x, a0.x); a0.y = fmaf(alA, v0.y, a0.y);
        a0.z = fmaf(alA, v0.z, a0.z); a0.w = fmaf(alA, v0.w, a0.w);
        a1.x = fmaf(alB, v1.x, a1.x); a1.y = fmaf(alB, v1.y, a1.y);
        a1.z = fmaf(alB, v1.z, a1.z); a1.w = fmaf(alB, v1.w, a1.w);
      }
      uint4 p0, p1;
      p0.x = pack_hl(fmaxf((a0.x * rsvA + bbA.x - bmA.x) * g0_ + btA.x, 0.f));
      p0.y = pack_hl(fmaxf((a0.y * rsvA + bbA.y - bmA.y) * g1_ + btA.y, 0.f));
      p0.z = pack_hl(fmaxf((a0.z * rsvA + bbA.z - bmA.z) * g2_ + btA.z, 0.f));
      p0.w = pack_hl(fmaxf((a0.w * rsvA + bbA.w - bmA.w) * g3_ + btA.w, 0.f));
      p1.x = pack_hl(fmaxf((a1.x * rsvB + bbB.x - bmB.x) * g4_ + btB.x, 0.f));
      p1.y = pack_hl(fmaxf((a1.y * rsvB + bbB.y - bmB.y) * g5_ + btB.y, 0.f));
      p1.z = pack_hl(fmaxf((a1.z * rsvB + bbB.z - bmB.z) * g6_ + btB.z, 0.f));
      p1.w = pack_hl(fmaxf((a1.w * rsvB + bbB.w - bmB.w) * g7_ + btB.w, 0.f));
      *(uint4*)(shl + n * RSW + c0) = p0;
      *(uint4*)(shl + n * RSW + c1) = p1;
    }
  }
  __syncthreads();

  // ======================= GAT layer 1 (1 head) =======================
  mfma_gemm_acc(shl, wf + 32768, t, acc);
  store_acc(sg, t, acc);
  __syncthreads();

  // logits: 1024-thread partials (8 per node), then 256-thread combine
  {
    const int n = t >> 3, c = t & 7;
    const float* row = sg + n * RSW + c * 16;
    float accs = 0.f, accd = 0.f;
    #pragma unroll
    for (int i = 0; i < 4; ++i) {
      const int d = i * 4;
      const float4 v  = *(const float4*)(row + d);
      const float4 as = *(const float4*)(g1as + c * 16 + d);
      const float4 ad = *(const float4*)(g1ad + c * 16 + d);
      accs += v.x*as.x + v.y*as.y + v.z*as.z + v.w*as.w;
      accd += v.x*ad.x + v.y*ad.y + v.z*ad.z + v.w*ad.w;
    }
    s_alpha[t] = accs;          // partials: [n*8+c]
    s_alpha[2048 + t] = accd;
  }
  __syncthreads();
  if (t < 256) {
    const int which = t >> 7, n = t & 127;
    const float* p = s_alpha + which * 2048 + n * 8;
    float s = 0.f;
    #pragma unroll
    for (int c = 0; c < 8; ++c) s += p[c];
    if (which == 0) s_es[n] = s; else s_ed[n] = s;
  }
  __syncthreads();

  // edge-parallel numerators (1 head)
  for (int i = t; i < ET; i += 1024) {
    const int sd = s_src[i];
    float v = s_es[sd & 127] + s_ed[sd >> 8];
    v = (v > 0.f) ? v : 0.2f * v;
    s_alpha[i] = __expf(v);
  }
  __syncthreads();

  // per-node 1/sum (s_ed dead post-numerators)
  if (t < FN) {
    const int e0 = s_rp[t], e1 = s_rp[t + 1];
    float sum = 0.f;
    for (int e = e0; e < e1; ++e) sum += s_alpha[e];
    s_ed[t] = 1.f / sum;
  }
  __syncthreads();

  // aggregation + epilogue -> shl
  {
    const int cg = t & 15, rg = t >> 4;
    const int c0 = cg * 4, c1 = 64 + cg * 4;
    const float4 bbA = *(const float4*)&g1b[c0],  bbB = *(const float4*)&g1b[c1];
    const float4 bmA = *(const float4*)&bn1m[c0], bmB = *(const float4*)&bn1m[c1];
    const float4 bvA = *(const float4*)&bn1v[c0], bvB = *(const float4*)&bn1v[c1];
    const float4 bgA = *(const float4*)&bn1g[c0], bgB = *(const float4*)&bn1g[c1];
    const float4 btA = *(const float4*)&bn1b[c0], btB = *(const float4*)&bn1b[c1];
    const float g0_ = bgA.x * rsqrtf(bvA.x + 1e-5f), g1_ = bgA.y * rsqrtf(bvA.y + 1e-5f);
    const float g2_ = bgA.z * rsqrtf(bvA.z + 1e-5f), g3_ = bgA.w * rsqrtf(bvA.w + 1e-5f);
    const float g4_ = bgB.x * rsqrtf(bvB.x + 1e-5f), g5_ = bgB.y * rsqrtf(bvB.y + 1e-5f);
    const float g6_ = bgB.z * rsqrtf(bvB.z + 1e-5f), g7_ = bgB.w * rsqrtf(bvB.w + 1e-5f);
    #pragma unroll
    for (int h2 = 0; h2 < 2; ++h2) {
      const int n = rg + h2 * 64;
      const int e0 = s_rp[n], e1 = s_rp[n + 1];
      const float rsv = s_ed[n];
      float4 a0 = make_float4(0.f, 0.f, 0.f, 0.f);
      float4 a1 = make_float4(0.f, 0.f, 0.f, 0.f);
      for (int e = e0; e < e1; ++e) {
        const int s = s_src[e] & 127;
        const float al = s_alpha[e];
        const float4 v0 = *(const float4*)(sg + s * RSW + c0);
        const float4 v1 = *(const float4*)(sg + s * RSW + c1);
        a0.x = fmaf(al, v0.x, a0.x); a0.y = fmaf(al, v0.y, a0.y);
        a0.z = fmaf(al, v0.z, a0.z); a0.w = fmaf(al, v0.w, a0.w);
        a1.x = fmaf(al, v1.x, a1.x); a1.y = fmaf(al, v1.y, a1.y);
        a1.z = fmaf(al, v1.z, a1.z); a1.w = fmaf(al, v1.w, a1.w);
      }
      uint4 p0, p1;
      p0.x = pack_hl(fmaxf((a0.x * rsv + bbA.x - bmA.x) * g0_ + btA.x, 0.f));
      p0.y = pack_hl(fmaxf((a0.y * rsv + bbA.y - bmA.y) * g1_ + btA.y, 0.f));
      p0.z = pack_hl(fmaxf((a0.z * rsv + bbA.z - bmA.z) * g2_ + btA.z, 0.f));
      p0.w = pack_hl(fmaxf((a0.w * rsv + bbA.w - bmA.w) * g3_ + btA.w, 0.f));
      p1.x = pack_hl(fmaxf((a1.x * rsv + bbB.x - bmB.x) * g4_ + btB.x, 0.f));
      p1.y = pack_hl(fmaxf((a1.y * rsv + bbB.y - bmB.y) * g5_ + btB.y, 0.f));
      p1.z = pack_hl(fmaxf((a1.z * rsv + bbB.z - bmB.z) * g6_ + btB.z, 0.f));
      p1.w = pack_hl(fmaxf((a1.w * rsv + bbB.w - bmB.w) * g7_ + btB.w, 0.f));
      *(uint4*)(shl + n * RSW + c0) = p0;
      *(uint4*)(shl + n * RSW + c1) = p1;
    }
  }
  __syncthreads();

  // ---- mean pool (packed shl) + MLP head
  float* s_red = s_alpha;
  {
    const int j = t & 127, q = t >> 7;
    float p = 0.f;
    for (int n = q * 16; n < q * 16 + 16; ++n) p += unpack_val(shl[n * RSW + j]);
    s_red[q * 128 + j] = p;
  }
  __syncthreads();
  if (t < FN) {
    float p = 0.f;
    #pragma unroll
    for (int q = 0; q < 8; ++q) p += s_red[q * 128 + t];
    s_es[t] = p * (1.f / 128.f);
  }
  __syncthreads();
  if (t < 512) {
    const int j = t & 63, part = t >> 6;
    float a = 0.f;
    #pragma unroll
    for (int k = part * 16; k < part * 16 + 16; ++k)
      a = fmaf(s_es[k], w1[k * 64 + j], a);
    s_ed[part * 64 + j] = a;
  }
  __syncthreads();
  if (t < 64) {
    float a = b1[t];
    #pragma unroll
    for (int p = 0; p < 8; ++p) a += s_ed[p * 64 + t];
    a = fmaxf(a, 0.f);
    float v = a * w2[t];
    #pragma unroll
    for (int off = 32; off > 0; off >>= 1) v += __shfl_down(v, off, 64);
    if (t == 0) out[b] = v + b2[0];
  }
}

extern "C" void kernel_launch(void* const* d_in, const int* in_sizes, int n_in,
                              void* d_out, int out_size, void* d_ws, size_t ws_size,
                              hipStream_t stream)
{
  const float* x    = (const float*)d_in[0];
  const int*   ei   = (const int*)d_in[1];
  const float* w_in = (const float*)d_in[2];
  const float* b_in = (const float*)d_in[3];
  const float* g0w  = (const float*)d_in[4];
  const float* g0as = (const float*)d_in[5];
  const float* g0ad = (const float*)d_in[6];
  const float* g0b  = (const float*)d_in[7];
  const float* bn0g = (const float*)d_in[8];
  const float* bn0b = (const float*)d_in[9];
  const float* bn0m = (const float*)d_in[10];
  const float* bn0v = (const float*)d_in[11];
  const float* g1w  = (const float*)d_in[12];
  const float* g1as = (const float*)d_in[13];
  const float* g1ad = (const float*)d_in[14];
  const float* g1b  = (const float*)d_in[15];
  const float* bn1g = (const float*)d_in[16];
  const float* bn1b = (const float*)d_in[17];
  const float* bn1m = (const float*)d_in[18];
  const float* bn1v = (const float*)d_in[19];
  const float* w1   = (const float*)d_in[20];
  const float* b1   = (const float*)d_in[21];
  const float* w2   = (const float*)d_in[22];
  const float* b2   = (const float*)d_in[23];

  u16* wf = (u16*)d_ws;   // 2 layers x 2 hilo x 16384 bf16 = 128 KB

  prep_w_kernel<<<128, 256, 0, stream>>>(g0w, g1w, wf);
  gnn_fused_kernel<<<1024, 1024, 0, stream>>>(x, ei, w_in, b_in,
      g0as, g0ad, g0b, bn0g, bn0b, bn0m, bn0v,
      g1as, g1ad, g1b, bn1g, bn1b, bn1m, bn1v,
      w1, b1, w2, b2, wf, (float*)d_out);
}

// Round 14
// 195.407 us; speedup vs baseline: 1.2128x; 1.0057x over previous
//
#include <hip/hip_runtime.h>

#define FN   128    // nodes per graph
#define HDIM 128    // hidden dim
#define NH   4      // heads, layer 0
#define HSZ  32     // head dim, layer 0
#define EB   1024   // base edges per graph
#define ET   1152   // edges incl. self loops
#define RSW  132    // padded LDS row stride (words)

typedef __attribute__((ext_vector_type(8))) short bf16x8;
typedef __attribute__((ext_vector_type(4))) float f32x4;
typedef unsigned int u32;
typedef unsigned short u16;

union U8 { bf16x8 v; u32 u[4]; };

__device__ __forceinline__ u32 pack_hl(float v) {
  const u32 u = __float_as_uint(v);
  const u32 hib = u & 0xFFFF0000u;
  const float lo = v - __uint_as_float(hib);
  return hib | (__float_as_uint(lo) >> 16);
}
__device__ __forceinline__ float unpack_val(u32 p) {
  return __uint_as_float(p & 0xFFFF0000u) + __uint_as_float(p << 16);
}
__device__ __forceinline__ float lrelu(float v) {
  return (v > 0.f) ? v : 0.2f * v;
}

__device__ __forceinline__ void unpack_frag(const u32* __restrict__ q,
                                            bf16x8& hi, bf16x8& lo)
{
  const uint4 p0 = *(const uint4*)(q);
  const uint4 p1 = *(const uint4*)(q + 4);
  U8 H, L;
  H.u[0] = (p0.x >> 16) | (p0.y & 0xFFFF0000u);
  L.u[0] = (p0.x & 0xFFFFu) | (p0.y << 16);
  H.u[1] = (p0.z >> 16) | (p0.w & 0xFFFF0000u);
  L.u[1] = (p0.z & 0xFFFFu) | (p0.w << 16);
  H.u[2] = (p1.x >> 16) | (p1.y & 0xFFFF0000u);
  L.u[2] = (p1.x & 0xFFFFu) | (p1.y << 16);
  H.u[3] = (p1.z >> 16) | (p1.w & 0xFFFF0000u);
  L.u[3] = (p1.z & 0xFFFFu) | (p1.w << 16);
  hi = H.v; lo = L.v;
}

// ---------------- W -> split bf16 hi/lo, B-fragment layout (r3-verified) ----
__global__ __launch_bounds__(256) void prep_w_kernel(
    const float* __restrict__ g0w, const float* __restrict__ g1w,
    u16* __restrict__ wf)
{
  const int idx = blockIdx.x * 256 + threadIdx.x;   // 32768 total
  const int layer = idx >> 14;
  const int r = idx & 16383;
  const int c  = r >> 11;
  const int kc = (r >> 9) & 3;
  const int l  = (r >> 3) & 63;
  const int j  = r & 7;
  const int k = kc * 32 + (l >> 4) * 8 + j;
  const int n = c * 16 + (l & 15);
  const float* W = layer ? g1w : g0w;
  const float v = W[k * HDIM + n];
  const u32 u = __float_as_uint(v);
  const u32 hib = u & 0xFFFF0000u;
  const float lo = v - __uint_as_float(hib);
  wf[layer * 32768 + r]         = (u16)(u >> 16);
  wf[layer * 32768 + 16384 + r] = (u16)(__float_as_uint(lo) >> 16);
}

// MFMA GEMM, 8 waves/graph (r12-verified math): wave tile 32 cols x 64 rows.
__device__ __forceinline__ void mfma_gemm_acc(const u32* __restrict__ F,
                                              const u16* __restrict__ wf,
                                              int lw, int lane, f32x4 acc[4][2])
{
  const int cg = lw & 3, rh = lw >> 2;
  const int m = lane & 15, quad = lane >> 4;

  #pragma unroll
  for (int s = 0; s < 4; ++s)
    #pragma unroll
    for (int ct = 0; ct < 2; ++ct) acc[s][ct] = (f32x4){0.f, 0.f, 0.f, 0.f};

  const u16* bbase = wf + (cg * 8) * 512 + lane * 8;   // ct +2048, kc +512

  #pragma unroll
  for (int kc = 0; kc < 4; ++kc) {
    bf16x8 bhi[2], blo[2];
    #pragma unroll
    for (int ct = 0; ct < 2; ++ct) {
      const u16* bp = bbase + ct * 2048 + kc * 512;
      bhi[ct] = *(const bf16x8*)bp;
      blo[ct] = *(const bf16x8*)(bp + 16384);
    }
    #pragma unroll
    for (int s = 0; s < 4; ++s) {
      const u32* ap = F + (rh * 64 + s * 16 + m) * RSW + quad * 8 + kc * 32;
      bf16x8 ahi, alo;
      unpack_frag(ap, ahi, alo);
      #pragma unroll
      for (int ct = 0; ct < 2; ++ct) {
        acc[s][ct] = __builtin_amdgcn_mfma_f32_16x16x32_bf16(ahi, bhi[ct], acc[s][ct], 0, 0, 0);
        acc[s][ct] = __builtin_amdgcn_mfma_f32_16x16x32_bf16(alo, bhi[ct], acc[s][ct], 0, 0, 0);
        acc[s][ct] = __builtin_amdgcn_mfma_f32_16x16x32_bf16(ahi, blo[ct], acc[s][ct], 0, 0, 0);
      }
    }
  }
}

// store acc -> plain f32 (in-place into F); C/D: col = lane&15, row = quad*4+r
__device__ __forceinline__ void store_acc(float* __restrict__ sg, int lw,
                                          int lane, const f32x4 acc[4][2])
{
  const int cg = lw & 3, rh = lw >> 2;
  const int m = lane & 15, quad = lane >> 4;
  #pragma unroll
  for (int s = 0; s < 4; ++s) {
    const int row0 = rh * 64 + s * 16 + quad * 4;
    #pragma unroll
    for (int ct = 0; ct < 2; ++ct)
      #pragma unroll
      for (int r = 0; r < 4; ++r)
        sg[(row0 + r) * RSW + cg * 32 + ct * 16 + m] = acc[s][ct][r];
  }
}

// ---------------- fused GNN: 1024 threads, TWO graphs per block ------------
__global__ __launch_bounds__(1024) void gnn_fused_kernel(
    const float* __restrict__ x, const int* __restrict__ ei,
    const float* __restrict__ w_in, const float* __restrict__ b_in,
    const float* __restrict__ g0as, const float* __restrict__ g0ad,
    const float* __restrict__ g0b,
    const float* __restrict__ bn0g, const float* __restrict__ bn0b,
    const float* __restrict__ bn0m, const float* __restrict__ bn0v,
    const float* __restrict__ g1as, const float* __restrict__ g1ad,
    const float* __restrict__ g1b,
    const float* __restrict__ bn1g, const float* __restrict__ bn1b,
    const float* __restrict__ bn1m, const float* __restrict__ bn1v,
    const float* __restrict__ w1, const float* __restrict__ b1,
    const float* __restrict__ w2, const float* __restrict__ b2,
    const u16* __restrict__ wf,
    float* __restrict__ out)
{
  __shared__ u32   Fb[2 * FN * RSW];   // 135168 B: per-graph packed feat <-> f32 sg
  __shared__ int   s_src[ET];          // src | dst<<8 (SHARED topology)
  __shared__ int   s_rp[FN + 1];
  __shared__ float s_scr[3072];        // per graph: es 512 | ed 512 | rs 512

  const int t = threadIdx.x;
  const int b = blockIdx.x;
  const int g = t >> 9;                // graph within block
  const int u = t & 511;               // per-graph thread
  const int lane = t & 63;
  const int lw = (t >> 6) & 7;         // per-graph wave
  u32*   F    = Fb + g * (FN * RSW);
  float* s_es = s_scr + g * 1536;
  float* s_ed = s_es + 512;
  float* s_rs = s_es + 1024;
  f32x4 acc[4][2];

  // ================= shared CSR build =================
  int* s_deg  = (int*)s_scr;
  int* s_fill = s_deg + 128;
  const int e_dst = ei[EB + t];
  const int e_src = ei[t];
  if (t < 2 * FN) s_deg[t] = 0;
  __syncthreads();
  atomicAdd(&s_deg[e_dst], 1);

  // ---- input projection + ReLU -> F (packed), per graph
  {
    const int j = u & 127, q = u >> 7;
    const float wv = w_in[j], bv = b_in[j];
    const size_t xb = (size_t)(b * 2 + g) * FN;
    for (int n = q * 32; n < q * 32 + 32; ++n) {
      const float v = fmaxf(fmaf(x[xb + n], wv, bv), 0.f);
      F[n * RSW + j] = pack_hl(v);
    }
  }
  __syncthreads();
  if (t < 64) {                         // wave-0 exclusive scan of (deg+1)
    const int v0 = s_deg[2 * t] + 1, v1 = s_deg[2 * t + 1] + 1;
    const int p = v0 + v1;
    int sc = p;
    #pragma unroll
    for (int off = 1; off < 64; off <<= 1) {
      const int o = __shfl_up(sc, off, 64);
      if (t >= off) sc += o;
    }
    s_rp[2 * t] = sc - p;
    s_rp[2 * t + 1] = sc - v1;
    if (t == 63) s_rp[128] = sc;        // == ET
  }
  __syncthreads();
  {
    const int p = s_rp[e_dst] + atomicAdd(&s_fill[e_dst], 1);
    s_src[p] = e_src | (e_dst << 8);
  }
  if (t < FN) s_src[s_rp[t + 1] - 1] = t | (t << 8);
  __syncthreads();

  // ======================= GAT layer 0 =======================
  mfma_gemm_acc(F, wf, lw, lane, acc);
  __syncthreads();                       // all packed reads done
  store_acc((float*)F, lw, lane, acc);   // F now f32 sg
  __syncthreads();

  // logits per (head, node)
  {
    const int hh = u >> 7, n = u & 127;
    const float* row = (const float*)F + n * RSW + hh * HSZ;
    float accs = 0.f, accd = 0.f;
    #pragma unroll
    for (int s = 0; s < 8; ++s) {
      const int d = ((n + s) & 7) * 4;
      const float4 v  = *(const float4*)(row + d);
      const float4 as = *(const float4*)(g0as + hh * HSZ + d);
      const float4 ad = *(const float4*)(g0ad + hh * HSZ + d);
      accs += v.x*as.x + v.y*as.y + v.z*as.z + v.w*as.w;
      accd += v.x*ad.x + v.y*ad.y + v.z*ad.z + v.w*ad.w;
    }
    s_es[hh * 128 + n] = accs;
    s_ed[hh * 128 + n] = accd;
  }
  __syncthreads();

  // per-(head,node) 1/sum, exp computed once here (no-max: r7-verified)
  {
    const int hh = u >> 7, n = u & 127;
    const int e0 = s_rp[n], e1 = s_rp[n + 1];
    const float edv = s_ed[hh * 128 + n];
    const float* esb = s_es + hh * 128;
    float sum = 0.f;
    for (int e = e0; e < e1; ++e)
      sum += __expf(lrelu(esb[s_src[e] & 127] + edv));
    s_rs[hh * 128 + n] = 1.f / sum;
  }
  __syncthreads();

  // aggregation (exp recomputed per edge) -> regs -> in-place writeback
  {
    const int cg = u & 15, rg = u >> 4;       // cg: col group, rg: 0..31
    const int c0 = cg * 4, c1 = 64 + cg * 4;
    const int hhA = cg >> 3, hhB = 2 + hhA;
    const float* Ff = (const float*)F;
    const float* esA = s_es + hhA * 128;
    const float* esB = s_es + hhB * 128;
    float4 aA[4], aB[4];
    #pragma unroll
    for (int h2 = 0; h2 < 4; ++h2) {
      const int n = rg + h2 * 32;
      const int e0 = s_rp[n], e1 = s_rp[n + 1];
      const float edvA = s_ed[hhA * 128 + n], edvB = s_ed[hhB * 128 + n];
      const float rsvA = s_rs[hhA * 128 + n], rsvB = s_rs[hhB * 128 + n];
      float4 a0 = make_float4(0.f, 0.f, 0.f, 0.f);
      float4 a1 = make_float4(0.f, 0.f, 0.f, 0.f);
      for (int e = e0; e < e1; ++e) {
        const int s = s_src[e] & 127;
        const float alA = __expf(lrelu(esA[s] + edvA));
        const float alB = __expf(lrelu(esB[s] + edvB));
        const float4 v0 = *(const float4*)(Ff + s * RSW + c0);
        const float4 v1 = *(const float4*)(Ff + s * RSW + c1);
        a0.x = fmaf(alA, v0.x, a0.x); a0.y = fmaf(alA, v0.y, a0.y);
        a0.z = fmaf(alA, v0.z, a0.z); a0.w = fmaf(alA, v0.w, a0.w);
        a1.x = fmaf(alB, v1.x, a1.x); a1.y = fmaf(alB, v1.y, a1.y);
        a1.z = fmaf(alB, v1.z, a1.z); a1.w = fmaf(alB, v1.w, a1.w);
      }
      aA[h2].x = a0.x * rsvA; aA[h2].y = a0.y * rsvA;
      aA[h2].z = a0.z * rsvA; aA[h2].w = a0.w * rsvA;
      aB[h2].x = a1.x * rsvB; aB[h2].y = a1.y * rsvB;
      aB[h2].z = a1.z * rsvB; aB[h2].w = a1.w * rsvB;
    }
    __syncthreads();                     // all sg reads done -> overwrite F
    {
      const float4 bb = *(const float4*)&g0b[c0];
      const float4 bm = *(const float4*)&bn0m[c0];
      const float4 bv = *(const float4*)&bn0v[c0];
      const float4 bg = *(const float4*)&bn0g[c0];
      const float4 bt = *(const float4*)&bn0b[c0];
      const float q0 = bg.x * rsqrtf(bv.x + 1e-5f), q1 = bg.y * rsqrtf(bv.y + 1e-5f);
      const float q2 = bg.z * rsqrtf(bv.z + 1e-5f), q3 = bg.w * rsqrtf(bv.w + 1e-5f);
      #pragma unroll
      for (int h2 = 0; h2 < 4; ++h2) {
        const int n = rg + h2 * 32;
        uint4 p;
        p.x = pack_hl(fmaxf((aA[h2].x + bb.x - bm.x) * q0 + bt.x, 0.f));
        p.y = pack_hl(fmaxf((aA[h2].y + bb.y - bm.y) * q1 + bt.y, 0.f));
        p.z = pack_hl(fmaxf((aA[h2].z + bb.z - bm.z) * q2 + bt.z, 0.f));
        p.w = pack_hl(fmaxf((aA[h2].w + bb.w - bm.w) * q3 + bt.w, 0.f));
        *(uint4*)(F + n * RSW + c0) = p;
      }
    }
    {
      const float4 bb = *(const float4*)&g0b[c1];
      const float4 bm = *(const float4*)&bn0m[c1];
      const float4 bv = *(const float4*)&bn0v[c1];
      const float4 bg = *(const float4*)&bn0g[c1];
      const float4 bt = *(const float4*)&bn0b[c1];
      const float q0 = bg.x * rsqrtf(bv.x + 1e-5f), q1 = bg.y * rsqrtf(bv.y + 1e-5f);
      const float q2 = bg.z * rsqrtf(bv.z + 1e-5f), q3 = bg.w * rsqrtf(bv.w + 1e-5f);
      #pragma unroll
      for (int h2 = 0; h2 < 4; ++h2) {
        const int n = rg + h2 * 32;
        uint4 p;
        p.x = pack_hl(fmaxf((aB[h2].x + bb.x - bm.x) * q0 + bt.x, 0.f));
        p.y = pack_hl(fmaxf((aB[h2].y + bb.y - bm.y) * q1 + bt.y, 0.f));
        p.z = pack_hl(fmaxf((aB[h2].z + bb.z - bm.z) * q2 + bt.z, 0.f));
        p.w = pack_hl(fmaxf((aB[h2].w + bb.w - bm.w) * q3 + bt.w, 0.f));
        *(uint4*)(F + n * RSW + c1) = p;
      }
    }
  }
  __syncthreads();

  // ======================= GAT layer 1 (1 head) =======================
  mfma_gemm_acc(F, wf + 32768, lw, lane, acc);
  __syncthreads();
  store_acc((float*)F, lw, lane, acc);
  __syncthreads();

  // logits partials: 512 threads/graph -> 4 partials per node
  {
    const int n = u >> 2, c = u & 3;
    const float* row = (const float*)F + n * RSW + c * 32;
    float accs = 0.f, accd = 0.f;
    #pragma unroll
    for (int i = 0; i < 8; ++i) {
      const int d = i * 4;
      const float4 v  = *(const float4*)(row + d);
      const float4 as = *(const float4*)(g1as + c * 32 + d);
      const float4 ad = *(const float4*)(g1ad + c * 32 + d);
      accs += v.x*as.x + v.y*as.y + v.z*as.z + v.w*as.w;
      accd += v.x*ad.x + v.y*ad.y + v.z*ad.z + v.w*ad.w;
    }
    s_es[u] = accs;                      // partials [n*4+c]
    s_ed[u] = accd;
  }
  __syncthreads();
  if (u < 128) {                         // combine -> s_rs[n]=es, s_rs[128+n]=ed
    const float* pe = s_es + u * 4;
    const float* pd = s_ed + u * 4;
    s_rs[u]       = pe[0] + pe[1] + pe[2] + pe[3];
    s_rs[128 + u] = pd[0] + pd[1] + pd[2] + pd[3];
  }
  __syncthreads();
  if (u < 128) {                         // 1/sum (exp once)
    const int e0 = s_rp[u], e1 = s_rp[u + 1];
    const float edv = s_rs[128 + u];
    float sum = 0.f;
    for (int e = e0; e < e1; ++e)
      sum += __expf(lrelu(s_rs[s_src[e] & 127] + edv));
    s_rs[256 + u] = 1.f / sum;
  }
  __syncthreads();

  // aggregation layer 1 -> regs -> in-place writeback
  {
    const int cg = u & 15, rg = u >> 4;
    const int c0 = cg * 4, c1 = 64 + cg * 4;
    const float* Ff = (const float*)F;
    float4 aA[4], aB[4];
    #pragma unroll
    for (int h2 = 0; h2 < 4; ++h2) {
      const int n = rg + h2 * 32;
      const int e0 = s_rp[n], e1 = s_rp[n + 1];
      const float edv = s_rs[128 + n];
      const float rsv = s_rs[256 + n];
      float4 a0 = make_float4(0.f, 0.f, 0.f, 0.f);
      float4 a1 = make_float4(0.f, 0.f, 0.f, 0.f);
      for (int e = e0; e < e1; ++e) {
        const int s = s_src[e] & 127;
        const float al = __expf(lrelu(s_rs[s] + edv));
        const float4 v0 = *(const float4*)(Ff + s * RSW + c0);
        const float4 v1 = *(const float4*)(Ff + s * RSW + c1);
        a0.x = fmaf(al, v0.x, a0.x); a0.y = fmaf(al, v0.y, a0.y);
        a0.z = fmaf(al, v0.z, a0.z); a0.w = fmaf(al, v0.w, a0.w);
        a1.x = fmaf(al, v1.x, a1.x); a1.y = fmaf(al, v1.y, a1.y);
        a1.z = fmaf(al, v1.z, a1.z); a1.w = fmaf(al, v1.w, a1.w);
      }
      aA[h2].x = a0.x * rsv; aA[h2].y = a0.y * rsv;
      aA[h2].z = a0.z * rsv; aA[h2].w = a0.w * rsv;
      aB[h2].x = a1.x * rsv; aB[h2].y = a1.y * rsv;
      aB[h2].z = a1.z * rsv; aB[h2].w = a1.w * rsv;
    }
    __syncthreads();
    {
      const float4 bb = *(const float4*)&g1b[c0];
      const float4 bm = *(const float4*)&bn1m[c0];
      const float4 bv = *(const float4*)&bn1v[c0];
      const float4 bg = *(const float4*)&bn1g[c0];
      const float4 bt = *(const float4*)&bn1b[c0];
      const float q0 = bg.x * rsqrtf(bv.x + 1e-5f), q1 = bg.y * rsqrtf(bv.y + 1e-5f);
      const float q2 = bg.z * rsqrtf(bv.z + 1e-5f), q3 = bg.w * rsqrtf(bv.w + 1e-5f);
      #pragma unroll
      for (int h2 = 0; h2 < 4; ++h2) {
        const int n = rg + h2 * 32;
        uint4 p;
        p.x = pack_hl(fmaxf((aA[h2].x + bb.x - bm.x) * q0 + bt.x, 0.f));
        p.y = pack_hl(fmaxf((aA[h2].y + bb.y - bm.y) * q1 + bt.y, 0.f));
        p.z = pack_hl(fmaxf((aA[h2].z + bb.z - bm.z) * q2 + bt.z, 0.f));
        p.w = pack_hl(fmaxf((aA[h2].w + bb.w - bm.w) * q3 + bt.w, 0.f));
        *(uint4*)(F + n * RSW + c0) = p;
      }
    }
    {
      const float4 bb = *(const float4*)&g1b[c1];
      const float4 bm = *(const float4*)&bn1m[c1];
      const float4 bv = *(const float4*)&bn1v[c1];
      const float4 bg = *(const float4*)&bn1g[c1];
      const float4 bt = *(const float4*)&bn1b[c1];
      const float q0 = bg.x * rsqrtf(bv.x + 1e-5f), q1 = bg.y * rsqrtf(bv.y + 1e-5f);
      const float q2 = bg.z * rsqrtf(bv.z + 1e-5f), q3 = bg.w * rsqrtf(bv.w + 1e-5f);
      #pragma unroll
      for (int h2 = 0; h2 < 4; ++h2) {
        const int n = rg + h2 * 32;
        uint4 p;
        p.x = pack_hl(fmaxf((aB[h2].x + bb.x - bm.x) * q0 + bt.x, 0.f));
        p.y = pack_hl(fmaxf((aB[h2].y + bb.y - bm.y) * q1 + bt.y, 0.f));
        p.z = pack_hl(fmaxf((aB[h2].z + bb.z - bm.z) * q2 + bt.z, 0.f));
        p.w = pack_hl(fmaxf((aB[h2].w + bb.w - bm.w) * q3 + bt.w, 0.f));
        *(uint4*)(F + n * RSW + c1) = p;
      }
    }
  }
  __syncthreads();

  // ---- mean pool (packed F) + MLP head, per graph
  {
    const int j = u & 127, q = u >> 7;
    float p = 0.f;
    for (int n = q * 32; n < q * 32 + 32; ++n) p += unpack_val(F[n * RSW + j]);
    s_es[q * 128 + j] = p;
  }
  __syncthreads();
  if (u < 128) {
    s_ed[u] = (s_es[u] + s_es[u + 128] + s_es[u + 256] + s_es[u + 384])
              * (1.f / 128.f);
  }
  __syncthreads();
  {
    const int j = u & 63, part = u >> 6;
    float a = 0.f;
    #pragma unroll
    for (int k = part * 16; k < part * 16 + 16; ++k)
      a = fmaf(s_ed[k], w1[k * 64 + j], a);
    s_rs[part * 64 + j] = a;
  }
  __syncthreads();
  if (u < 64) {
    float a = b1[u];
    #pragma unroll
    for (int p = 0; p < 8; ++p) a += s_rs[p * 64 + u];
    a = fmaxf(a, 0.f);
    float v = a * w2[u];
    #pragma unroll
    for (int off = 32; off > 0; off >>= 1) v += __shfl_down(v, off, 64);
    if (u == 0) out[b * 2 + g] = v + b2[0];
  }
}

extern "C" void kernel_launch(void* const* d_in, const int* in_sizes, int n_in,
                              void* d_out, int out_size, void* d_ws, size_t ws_size,
                              hipStream_t stream)
{
  const float* x    = (const float*)d_in[0];
  const int*   ei   = (const int*)d_in[1];
  const float* w_in = (const float*)d_in[2];
  const float* b_in = (const float*)d_in[3];
  const float* g0w  = (const float*)d_in[4];
  const float* g0as = (const float*)d_in[5];
  const float* g0ad = (const float*)d_in[6];
  const float* g0b  = (const float*)d_in[7];
  const float* bn0g = (const float*)d_in[8];
  const float* bn0b = (const float*)d_in[9];
  const float* bn0m = (const float*)d_in[10];
  const float* bn0v = (const float*)d_in[11];
  const float* g1w  = (const float*)d_in[12];
  const float* g1as = (const float*)d_in[13];
  const float* g1ad = (const float*)d_in[14];
  const float* g1b  = (const float*)d_in[15];
  const float* bn1g = (const float*)d_in[16];
  const float* bn1b = (const float*)d_in[17];
  const float* bn1m = (const float*)d_in[18];
  const float* bn1v = (const float*)d_in[19];
  const float* w1   = (const float*)d_in[20];
  const float* b1   = (const float*)d_in[21];
  const float* w2   = (const float*)d_in[22];
  const float* b2   = (const float*)d_in[23];

  u16* wf = (u16*)d_ws;   // 2 layers x 2 hilo x 16384 bf16 = 128 KB

  prep_w_kernel<<<128, 256, 0, stream>>>(g0w, g1w, wf);
  gnn_fused_kernel<<<512, 1024, 0, stream>>>(x, ei, w_in, b_in,
      g0as, g0ad, g0b, bn0g, bn0b, bn0m, bn0v,
      g1as, g1ad, g1b, bn1g, bn1b, bn1m, bn1v,
      w1, b1, w2, b2, wf, (float*)d_out);
}

// Round 15
// 192.565 us; speedup vs baseline: 1.2307x; 1.0148x over previous
//
#include <hip/hip_runtime.h>

#define FN   128    // nodes per graph
#define HDIM 128    // hidden dim
#define NH   4      // heads, layer 0
#define HSZ  32     // head dim, layer 0
#define EB   1024   // base edges per graph
#define ET   1152   // edges incl. self loops
#define RSW  132    // padded LDS row stride (words)

typedef __attribute__((ext_vector_type(8))) short bf16x8;
typedef __attribute__((ext_vector_type(4))) float f32x4;
typedef unsigned int u32;
typedef unsigned short u16;

union U8 { bf16x8 v; u32 u[4]; };

__device__ __forceinline__ u32 pack_hl(float v) {
  const u32 u = __float_as_uint(v);
  const u32 hib = u & 0xFFFF0000u;
  const float lo = v - __uint_as_float(hib);
  return hib | (__float_as_uint(lo) >> 16);
}
__device__ __forceinline__ float unpack_val(u32 p) {
  return __uint_as_float(p & 0xFFFF0000u) + __uint_as_float(p << 16);
}
__device__ __forceinline__ float lrelu(float v) {
  return (v > 0.f) ? v : 0.2f * v;
}

__device__ __forceinline__ void unpack_frag(const u32* __restrict__ q,
                                            bf16x8& hi, bf16x8& lo)
{
  const uint4 p0 = *(const uint4*)(q);
  const uint4 p1 = *(const uint4*)(q + 4);
  U8 H, L;
  H.u[0] = (p0.x >> 16) | (p0.y & 0xFFFF0000u);
  L.u[0] = (p0.x & 0xFFFFu) | (p0.y << 16);
  H.u[1] = (p0.z >> 16) | (p0.w & 0xFFFF0000u);
  L.u[1] = (p0.z & 0xFFFFu) | (p0.w << 16);
  H.u[2] = (p1.x >> 16) | (p1.y & 0xFFFF0000u);
  L.u[2] = (p1.x & 0xFFFFu) | (p1.y << 16);
  H.u[3] = (p1.z >> 16) | (p1.w & 0xFFFF0000u);
  L.u[3] = (p1.z & 0xFFFFu) | (p1.w << 16);
  hi = H.v; lo = L.v;
}

// ---------------- W -> split bf16 hi/lo, B-fragment layout (r3-verified) ----
__global__ __launch_bounds__(256) void prep_w_kernel(
    const float* __restrict__ g0w, const float* __restrict__ g1w,
    u16* __restrict__ wf)
{
  const int idx = blockIdx.x * 256 + threadIdx.x;   // 32768 total
  const int layer = idx >> 14;
  const int r = idx & 16383;
  const int c  = r >> 11;
  const int kc = (r >> 9) & 3;
  const int l  = (r >> 3) & 63;
  const int j  = r & 7;
  const int k = kc * 32 + (l >> 4) * 8 + j;
  const int n = c * 16 + (l & 15);
  const float* W = layer ? g1w : g0w;
  const float v = W[k * HDIM + n];
  const u32 u = __float_as_uint(v);
  const u32 hib = u & 0xFFFF0000u;
  const float lo = v - __uint_as_float(hib);
  wf[layer * 32768 + r]         = (u16)(u >> 16);
  wf[layer * 32768 + 16384 + r] = (u16)(__float_as_uint(lo) >> 16);
}

// MFMA GEMM, 8 waves/graph (r12/r14-verified): wave tile 32 cols x 64 rows.
__device__ __forceinline__ void mfma_gemm_acc(const u32* __restrict__ F,
                                              const u16* __restrict__ wf,
                                              int lw, int lane, f32x4 acc[4][2])
{
  const int cg = lw & 3, rh = lw >> 2;
  const int m = lane & 15, quad = lane >> 4;

  #pragma unroll
  for (int s = 0; s < 4; ++s)
    #pragma unroll
    for (int ct = 0; ct < 2; ++ct) acc[s][ct] = (f32x4){0.f, 0.f, 0.f, 0.f};

  const u16* bbase = wf + (cg * 8) * 512 + lane * 8;   // ct +2048, kc +512

  #pragma unroll
  for (int kc = 0; kc < 4; ++kc) {
    bf16x8 bhi[2], blo[2];
    #pragma unroll
    for (int ct = 0; ct < 2; ++ct) {
      const u16* bp = bbase + ct * 2048 + kc * 512;
      bhi[ct] = *(const bf16x8*)bp;
      blo[ct] = *(const bf16x8*)(bp + 16384);
    }
    #pragma unroll
    for (int s = 0; s < 4; ++s) {
      const u32* ap = F + (rh * 64 + s * 16 + m) * RSW + quad * 8 + kc * 32;
      bf16x8 ahi, alo;
      unpack_frag(ap, ahi, alo);
      #pragma unroll
      for (int ct = 0; ct < 2; ++ct) {
        acc[s][ct] = __builtin_amdgcn_mfma_f32_16x16x32_bf16(ahi, bhi[ct], acc[s][ct], 0, 0, 0);
        acc[s][ct] = __builtin_amdgcn_mfma_f32_16x16x32_bf16(alo, bhi[ct], acc[s][ct], 0, 0, 0);
        acc[s][ct] = __builtin_amdgcn_mfma_f32_16x16x32_bf16(ahi, blo[ct], acc[s][ct], 0, 0, 0);
      }
    }
  }
}

// store acc -> plain f32 (in-place into F); C/D: col = lane&15, row = quad*4+r
__device__ __forceinline__ void store_acc(float* __restrict__ sg, int lw,
                                          int lane, const f32x4 acc[4][2])
{
  const int cg = lw & 3, rh = lw >> 2;
  const int m = lane & 15, quad = lane >> 4;
  #pragma unroll
  for (int s = 0; s < 4; ++s) {
    const int row0 = rh * 64 + s * 16 + quad * 4;
    #pragma unroll
    for (int ct = 0; ct < 2; ++ct)
      #pragma unroll
      for (int r = 0; r < 4; ++r)
        sg[(row0 + r) * RSW + cg * 32 + ct * 16 + m] = acc[s][ct][r];
  }
}

// ---------------- fused GNN: 1024 threads, TWO graphs per block ------------
__global__ __launch_bounds__(1024) void gnn_fused_kernel(
    const float* __restrict__ x, const int* __restrict__ ei,
    const float* __restrict__ w_in, const float* __restrict__ b_in,
    const float* __restrict__ g0as, const float* __restrict__ g0ad,
    const float* __restrict__ g0b,
    const float* __restrict__ bn0g, const float* __restrict__ bn0b,
    const float* __restrict__ bn0m, const float* __restrict__ bn0v,
    const float* __restrict__ g1as, const float* __restrict__ g1ad,
    const float* __restrict__ g1b,
    const float* __restrict__ bn1g, const float* __restrict__ bn1b,
    const float* __restrict__ bn1m, const float* __restrict__ bn1v,
    const float* __restrict__ w1, const float* __restrict__ b1,
    const float* __restrict__ w2, const float* __restrict__ b2,
    const u16* __restrict__ wf,
    float* __restrict__ out)
{
  __shared__ u32   Fb[2 * FN * RSW];   // 135168 B: per-graph packed feat <-> f32 sg
  __shared__ int   s_src[ET];          // src | dst<<8 (SHARED topology)
  __shared__ int   s_rp[FN + 1];
  __shared__ float s_scr[3072];        // per graph: es 512 | ed 512 | rs 512
  __shared__ float s_bn[512];          // folded BN consts: [l*256 + {q:0,r:128} + col]

  const int t = threadIdx.x;
  const int b = blockIdx.x;
  const int g = t >> 9;                // graph within block
  const int u = t & 511;               // per-graph thread
  const int lane = t & 63;
  const int lw = (t >> 6) & 7;         // per-graph wave
  u32*   F    = Fb + g * (FN * RSW);
  float* s_es = s_scr + g * 1536;
  float* s_ed = s_es + 512;
  float* s_rs = s_es + 1024;
  f32x4 acc[4][2];

  // ================= shared CSR build =================
  int* s_deg  = (int*)s_scr;
  int* s_fill = s_deg + 128;
  const int e_dst = ei[EB + t];
  const int e_src = ei[t];
  if (t < 2 * FN) s_deg[t] = 0;
  __syncthreads();
  atomicAdd(&s_deg[e_dst], 1);

  // ---- input projection + ReLU -> F (packed), per graph
  {
    const int j = u & 127, q = u >> 7;
    const float wv = w_in[j], bv = b_in[j];
    const size_t xb = (size_t)(b * 2 + g) * FN;
    for (int n = q * 32; n < q * 32 + 32; ++n) {
      const float v = fmaxf(fmaf(x[xb + n], wv, bv), 0.f);
      F[n * RSW + j] = pack_hl(v);
    }
  }
  __syncthreads();
  if (t < 64) {                         // wave-0 exclusive scan of (deg+1)
    const int v0 = s_deg[2 * t] + 1, v1 = s_deg[2 * t + 1] + 1;
    const int p = v0 + v1;
    int sc = p;
    #pragma unroll
    for (int off = 1; off < 64; off <<= 1) {
      const int o = __shfl_up(sc, off, 64);
      if (t >= off) sc += o;
    }
    s_rp[2 * t] = sc - p;
    s_rp[2 * t + 1] = sc - v1;
    if (t == 63) s_rp[128] = sc;        // == ET
  } else if (t >= 512 && t < 768) {     // fold BN consts (idle waves)
    const int layer = (t >> 7) & 1;     // 512-639 -> 0, 640-767 -> 1
    const int col = t & 127;
    const float bb = layer ? g1b[col]  : g0b[col];
    const float bm = layer ? bn1m[col] : bn0m[col];
    const float bv = layer ? bn1v[col] : bn0v[col];
    const float bg = layer ? bn1g[col] : bn0g[col];
    const float bt = layer ? bn1b[col] : bn0b[col];
    const float q = bg * rsqrtf(bv + 1e-5f);
    s_bn[layer * 256 + col] = q;
    s_bn[layer * 256 + 128 + col] = (bb - bm) * q + bt;
  }
  __syncthreads();
  {
    const int p = s_rp[e_dst] + atomicAdd(&s_fill[e_dst], 1);
    s_src[p] = e_src | (e_dst << 8);
  }
  if (t < FN) s_src[s_rp[t + 1] - 1] = t | (t << 8);
  __syncthreads();

  // ======================= GAT layer 0 =======================
  mfma_gemm_acc(F, wf, lw, lane, acc);
  __syncthreads();                       // all packed reads done
  store_acc((float*)F, lw, lane, acc);   // F now f32 sg
  __syncthreads();

  // logits per (head, node)
  {
    const int hh = u >> 7, n = u & 127;
    const float* row = (const float*)F + n * RSW + hh * HSZ;
    float accs = 0.f, accd = 0.f;
    #pragma unroll
    for (int s = 0; s < 8; ++s) {
      const int d = ((n + s) & 7) * 4;
      const float4 v  = *(const float4*)(row + d);
      const float4 as = *(const float4*)(g0as + hh * HSZ + d);
      const float4 ad = *(const float4*)(g0ad + hh * HSZ + d);
      accs += v.x*as.x + v.y*as.y + v.z*as.z + v.w*as.w;
      accd += v.x*ad.x + v.y*ad.y + v.z*ad.z + v.w*ad.w;
    }
    s_es[hh * 128 + n] = accs;
    s_ed[hh * 128 + n] = accd;
  }
  __syncthreads();

  // ---- aggregation: thread = (node, head), 32 cols; self-computed sum;
  //      1 exp per edge; acc in 32 regs across in-place barrier
  {
    const int n = u & 127, hh = u >> 7;
    const int cb = hh * HSZ;
    const float* Ff = (const float*)F;
    const int e0 = s_rp[n], e1 = s_rp[n + 1];
    const float edv = s_ed[hh * 128 + n];
    const float* esb = s_es + hh * 128;
    float sum = 0.f;
    for (int e = e0; e < e1; ++e)
      sum += __expf(lrelu(esb[s_src[e] & 127] + edv));
    const float rsv = 1.f / sum;
    float4 a[8];
    #pragma unroll
    for (int i = 0; i < 8; ++i) a[i] = make_float4(0.f, 0.f, 0.f, 0.f);
    for (int e = e0; e < e1; ++e) {
      const int s = s_src[e] & 127;
      const float al = __expf(lrelu(esb[s] + edv));
      const float* rp_ = Ff + s * RSW + cb;
      #pragma unroll
      for (int i = 0; i < 8; ++i) {
        const float4 vv = *(const float4*)(rp_ + i * 4);
        a[i].x = fmaf(al, vv.x, a[i].x); a[i].y = fmaf(al, vv.y, a[i].y);
        a[i].z = fmaf(al, vv.z, a[i].z); a[i].w = fmaf(al, vv.w, a[i].w);
      }
    }
    __syncthreads();                     // all sg reads done -> overwrite F
    #pragma unroll
    for (int i = 0; i < 8; ++i) {
      const int col = cb + i * 4;
      const float4 q = *(const float4*)&s_bn[col];
      const float4 r = *(const float4*)&s_bn[128 + col];
      uint4 p;
      p.x = pack_hl(fmaxf(fmaf(a[i].x * rsv, q.x, r.x), 0.f));
      p.y = pack_hl(fmaxf(fmaf(a[i].y * rsv, q.y, r.y), 0.f));
      p.z = pack_hl(fmaxf(fmaf(a[i].z * rsv, q.z, r.z), 0.f));
      p.w = pack_hl(fmaxf(fmaf(a[i].w * rsv, q.w, r.w), 0.f));
      *(uint4*)(F + n * RSW + col) = p;
    }
  }
  __syncthreads();

  // ======================= GAT layer 1 (1 head) =======================
  mfma_gemm_acc(F, wf + 32768, lw, lane, acc);
  __syncthreads();
  store_acc((float*)F, lw, lane, acc);
  __syncthreads();

  // logits partials: 512 threads/graph -> 4 partials per node
  {
    const int n = u >> 2, c = u & 3;
    const float* row = (const float*)F + n * RSW + c * 32;
    float accs = 0.f, accd = 0.f;
    #pragma unroll
    for (int i = 0; i < 8; ++i) {
      const int d = i * 4;
      const float4 v  = *(const float4*)(row + d);
      const float4 as = *(const float4*)(g1as + c * 32 + d);
      const float4 ad = *(const float4*)(g1ad + c * 32 + d);
      accs += v.x*as.x + v.y*as.y + v.z*as.z + v.w*as.w;
      accd += v.x*ad.x + v.y*ad.y + v.z*ad.z + v.w*ad.w;
    }
    s_es[u] = accs;                      // partials [n*4+c]
    s_ed[u] = accd;
  }
  __syncthreads();
  if (u < 128) {                         // combine -> s_rs[n]=es, s_rs[128+n]=ed
    const float* pe = s_es + u * 4;
    const float* pd = s_ed + u * 4;
    s_rs[u]       = pe[0] + pe[1] + pe[2] + pe[3];
    s_rs[128 + u] = pd[0] + pd[1] + pd[2] + pd[3];
  }
  __syncthreads();

  // aggregation layer 1: thread = (node, col-quarter), self-computed sum
  {
    const int n = u & 127, cg = u >> 7;
    const int cb = cg * HSZ;
    const float* Ff = (const float*)F;
    const int e0 = s_rp[n], e1 = s_rp[n + 1];
    const float edv = s_rs[128 + n];
    float sum = 0.f;
    for (int e = e0; e < e1; ++e)
      sum += __expf(lrelu(s_rs[s_src[e] & 127] + edv));
    const float rsv = 1.f / sum;
    float4 a[8];
    #pragma unroll
    for (int i = 0; i < 8; ++i) a[i] = make_float4(0.f, 0.f, 0.f, 0.f);
    for (int e = e0; e < e1; ++e) {
      const int s = s_src[e] & 127;
      const float al = __expf(lrelu(s_rs[s] + edv));
      const float* rp_ = Ff + s * RSW + cb;
      #pragma unroll
      for (int i = 0; i < 8; ++i) {
        const float4 vv = *(const float4*)(rp_ + i * 4);
        a[i].x = fmaf(al, vv.x, a[i].x); a[i].y = fmaf(al, vv.y, a[i].y);
        a[i].z = fmaf(al, vv.z, a[i].z); a[i].w = fmaf(al, vv.w, a[i].w);
      }
    }
    __syncthreads();                     // all sg reads done -> overwrite F
    #pragma unroll
    for (int i = 0; i < 8; ++i) {
      const int col = cb + i * 4;
      const float4 q = *(const float4*)&s_bn[256 + col];
      const float4 r = *(const float4*)&s_bn[384 + col];
      uint4 p;
      p.x = pack_hl(fmaxf(fmaf(a[i].x * rsv, q.x, r.x), 0.f));
      p.y = pack_hl(fmaxf(fmaf(a[i].y * rsv, q.y, r.y), 0.f));
      p.z = pack_hl(fmaxf(fmaf(a[i].z * rsv, q.z, r.z), 0.f));
      p.w = pack_hl(fmaxf(fmaf(a[i].w * rsv, q.w, r.w), 0.f));
      *(uint4*)(F + n * RSW + col) = p;
    }
  }
  __syncthreads();

  // ---- mean pool (packed F) + MLP head, per graph
  {
    const int j = u & 127, q = u >> 7;
    float p = 0.f;
    for (int n = q * 32; n < q * 32 + 32; ++n) p += unpack_val(F[n * RSW + j]);
    s_es[q * 128 + j] = p;
  }
  __syncthreads();
  if (u < 128) {
    s_ed[u] = (s_es[u] + s_es[u + 128] + s_es[u + 256] + s_es[u + 384])
              * (1.f / 128.f);
  }
  __syncthreads();
  {
    const int j = u & 63, part = u >> 6;
    float a = 0.f;
    #pragma unroll
    for (int k = part * 16; k < part * 16 + 16; ++k)
      a = fmaf(s_ed[k], w1[k * 64 + j], a);
    s_rs[part * 64 + j] = a;
  }
  __syncthreads();
  if (u < 64) {
    float a = b1[u];
    #pragma unroll
    for (int p = 0; p < 8; ++p) a += s_rs[p * 64 + u];
    a = fmaxf(a, 0.f);
    float v = a * w2[u];
    #pragma unroll
    for (int off = 32; off > 0; off >>= 1) v += __shfl_down(v, off, 64);
    if (u == 0) out[b * 2 + g] = v + b2[0];
  }
}

extern "C" void kernel_launch(void* const* d_in, const int* in_sizes, int n_in,
                              void* d_out, int out_size, void* d_ws, size_t ws_size,
                              hipStream_t stream)
{
  const float* x    = (const float*)d_in[0];
  const int*   ei   = (const int*)d_in[1];
  const float* w_in = (const float*)d_in[2];
  const float* b_in = (const float*)d_in[3];
  const float* g0w  = (const float*)d_in[4];
  const float* g0as = (const float*)d_in[5];
  const float* g0ad = (const float*)d_in[6];
  const float* g0b  = (const float*)d_in[7];
  const float* bn0g = (const float*)d_in[8];
  const float* bn0b = (const float*)d_in[9];
  const float* bn0m = (const float*)d_in[10];
  const float* bn0v = (const float*)d_in[11];
  const float* g1w  = (const float*)d_in[12];
  const float* g1as = (const float*)d_in[13];
  const float* g1ad = (const float*)d_in[14];
  const float* g1b  = (const float*)d_in[15];
  const float* bn1g = (const float*)d_in[16];
  const float* bn1b = (const float*)d_in[17];
  const float* bn1m = (const float*)d_in[18];
  const float* bn1v = (const float*)d_in[19];
  const float* w1   = (const float*)d_in[20];
  const float* b1   = (const float*)d_in[21];
  const float* w2   = (const float*)d_in[22];
  const float* b2   = (const float*)d_in[23];

  u16* wf = (u16*)d_ws;   // 2 layers x 2 hilo x 16384 bf16 = 128 KB

  prep_w_kernel<<<128, 256, 0, stream>>>(g0w, g1w, wf);
  gnn_fused_kernel<<<512, 1024, 0, stream>>>(x, ei, w_in, b_in,
      g0as, g0ad, g0b, bn0g, bn0b, bn0m, bn0v,
      g1as, g1ad, g1b, bn1g, bn1b, bn1m, bn1v,
      w1, b1, w2, b2, wf, (float*)d_out);
}